// Round 6
// baseline (1988.457 us; speedup 1.0000x reference)
//
#include <hip/hip_runtime.h>
#include <hip/hip_bf16.h>

typedef __attribute__((ext_vector_type(4))) float f32x4;
typedef __attribute__((ext_vector_type(8))) short short8;
typedef __attribute__((ext_vector_type(8))) unsigned short ushort8;
typedef __attribute__((ext_vector_type(4))) unsigned short ushort4v;
typedef __attribute__((ext_vector_type(4))) unsigned int uint4v;

#define DEVFN __device__ __forceinline__

DEVFN float b2f(unsigned short u) { return __uint_as_float(((unsigned)u) << 16); }
DEVFN unsigned short f2b(float f) {
  __hip_bfloat16 h = __float2bfloat16(f);
  return __builtin_bit_cast(unsigned short, h);
}

DEVFN void load_lds16(const void* g, void* l) {
  __builtin_amdgcn_global_load_lds(
      (const __attribute__((address_space(1))) unsigned int*)g,
      (__attribute__((address_space(3))) unsigned int*)l, 16, 0, 0);
}

// ===========================================================================

__global__ void fill_out_zero(float* o, int n) {
  int i = blockIdx.x * 256 + threadIdx.x;
  if (i < n) o[i] = 0.0f;
}

__global__ __launch_bounds__(256) void init_x(
    const float* __restrict__ xin, const float* __restrict__ bvec,
    float* __restrict__ x, unsigned short* __restrict__ xb) {
  size_t i = (size_t)blockIdx.x * 256 + threadIdx.x;
  int col = (int)(i % 768);
  float v = xin[i] - bvec[col];
  x[i] = v;
  xb[i] = f2b(v);
}

// buf[i] = bias[i % ld] (or 0 if bias null)
__global__ __launch_bounds__(256) void fill_bias(
    float* __restrict__ buf, const float* __restrict__ bias, int ld) {
  size_t i = (size_t)blockIdx.x * 256 + threadIdx.x;
  buf[i] = bias ? bias[(int)(i % ld)] : 0.0f;
}

// f32 -> bf16 straight convert, 4 elems/thread (n must be /1024)
__global__ __launch_bounds__(256) void conv_f2b(
    const float* __restrict__ in, unsigned short* __restrict__ out) {
  size_t i = ((size_t)blockIdx.x * 256 + threadIdx.x) * 4;
  f32x4 v = *(const f32x4*)(in + i);
  ushort4v w;
#pragma unroll
  for (int e = 0; e < 4; ++e) w[e] = f2b(v[e]);
  *(ushort4v*)(out + i) = w;
}

// out[c][r] = bf16(in[r][c]); R,C multiples of 32; grid (R/32, C/32)
__global__ __launch_bounds__(256) void transpose_f2b(
    const float* __restrict__ in, unsigned short* __restrict__ out,
    int R, int C) {
  __shared__ float tile[32][33];
  int r0 = blockIdx.x * 32, c0 = blockIdx.y * 32;
  int tx = threadIdx.x & 31, ty = threadIdx.x >> 5;
#pragma unroll
  for (int i = 0; i < 4; ++i)
    tile[ty + i * 8][tx] = in[(size_t)(r0 + ty + i * 8) * C + c0 + tx];
  __syncthreads();
#pragma unroll
  for (int i = 0; i < 4; ++i)
    out[(size_t)(c0 + ty + i * 8) * R + r0 + tx] = f2b(tile[tx][ty + i * 8]);
}

// ---------------------------------------------------------------------------
// gemm_bt2: C[M,N] = epi(alpha * A[M,K] . B[N,K]^T + bias)  both bf16 K-major.
// 128x128 tile, BK=64, global_load_lds staging (conflict-free).
// SC=1: C rows shifted per batch (z storage [b][1+1024][W]).
// ---------------------------------------------------------------------------
template <typename CT, bool RELU, int SC, bool BIAS, bool SPLITK>
__global__ __launch_bounds__(256) void gemm_bt2(
    const unsigned short* __restrict__ A, const unsigned short* __restrict__ B,
    CT* __restrict__ C, const float* __restrict__ bias,
    int K, int ldc, float alpha) {
  __shared__ unsigned short sA[128 * 64];
  __shared__ unsigned short sB[128 * 64];
  const int tid = threadIdx.x;
  const int wave = tid >> 6, lane = tid & 63;
  const int row0 = blockIdx.x * 128, col0 = blockIdx.y * 128;
  const unsigned short* Ab = A + (size_t)row0 * K;
  const unsigned short* Bb = B + (size_t)col0 * K;
  const int srow = lane >> 3;
  const int scol = (lane & 7) * 8;
  const int wm = wave & 1, wn = wave >> 1;
  const int lr = lane & 15;
  const int lk = (lane >> 4) * 8;
  const int klen = SPLITK ? (K / (int)gridDim.z) : K;
  const int kbeg = SPLITK ? (int)blockIdx.z * klen : 0;
  f32x4 acc[4][4] = {};
  for (int k0 = kbeg; k0 < kbeg + klen; k0 += 64) {
#pragma unroll
    for (int it = 0; it < 4; ++it) {
      int chunk = wave * 4 + it;
      int r = chunk * 8 + srow;
      load_lds16(Ab + (size_t)r * K + k0 + scol, &sA[chunk * 512]);
      load_lds16(Bb + (size_t)r * K + k0 + scol, &sB[chunk * 512]);
    }
    __syncthreads();
#pragma unroll
    for (int ks = 0; ks < 2; ++ks) {
      short8 af[4], bfr[4];
#pragma unroll
      for (int i = 0; i < 4; ++i)
        af[i] = *(const short8*)&sA[(wm * 64 + i * 16 + lr) * 64 + ks * 32 + lk];
#pragma unroll
      for (int i = 0; i < 4; ++i)
        bfr[i] = *(const short8*)&sB[(wn * 64 + i * 16 + lr) * 64 + ks * 32 + lk];
#pragma unroll
      for (int i = 0; i < 4; ++i)
#pragma unroll
        for (int j = 0; j < 4; ++j)
          acc[i][j] = __builtin_amdgcn_mfma_f32_16x16x32_bf16(af[i], bfr[j], acc[i][j], 0, 0, 0);
    }
    __syncthreads();
  }
  const int rc = (SC == 0) ? 0 : ((row0 >> 10) + 1);
  const int rbase = row0 + rc + wm * 64 + (lane >> 4) * 4;
  const int cbase = col0 + wn * 64 + lr;
#pragma unroll
  for (int j = 0; j < 4; ++j) {
    int col = cbase + j * 16;
    float bv = BIAS ? bias[col] : 0.0f;
#pragma unroll
    for (int i = 0; i < 4; ++i) {
#pragma unroll
      for (int r = 0; r < 4; ++r) {
        float vv = acc[i][j][r] * alpha;
        size_t off = (size_t)(rbase + i * 16 + r) * ldc + col;
        if constexpr (SPLITK) {
          atomicAdd((float*)C + off, vv);
        } else {
          vv += bv;
          if (RELU) vv = fmaxf(vv, 0.0f);
          if constexpr (sizeof(CT) == 2) ((unsigned short*)C)[off] = f2b(vv);
          else C[off] = vv;
        }
      }
    }
  }
}

// ---------------------------------------------------------------------------
// gemm_qkv: C[4096,192] (f32, atomic) += A_zin . B[192,12288]^T
// BM=128, BN=192, BK=64, waves 2x2 (64x96 each); grid (32 rows, 8 k-splits).
// A is always the z_in view. SHIFT=1 (k/v): store row t -> t+1 within batch,
// dropping in-batch row 1023 (z_ctx shift done at write time).
// ---------------------------------------------------------------------------
template <int SHIFT>
__global__ __launch_bounds__(256) void gemm_qkv(
    const unsigned short* __restrict__ A, const unsigned short* __restrict__ B,
    float* __restrict__ C) {
  __shared__ unsigned short sA[128 * 64];   // 16 KB
  __shared__ unsigned short sB[192 * 64];   // 24 KB
  const int tid = threadIdx.x;
  const int wave = tid >> 6, lane = tid & 63;
  const int row0 = blockIdx.x * 128;
  const int ra = (row0 >> 10) + 1;          // z_in view
  const unsigned short* Ab = A + (size_t)(row0 + ra) * 12288;
  const int srow = lane >> 3;
  const int scol = (lane & 7) * 8;
  const int wm = wave & 1, wn = wave >> 1;
  const int lr = lane & 15;
  const int lk = (lane >> 4) * 8;
  const int kbeg = (int)blockIdx.y * 1536;  // 12288/8
  f32x4 acc[4][6] = {};
  for (int k0 = kbeg; k0 < kbeg + 1536; k0 += 64) {
    // 40 chunks of 8 rows: 0..15 = A, 16..39 = B; 10 per wave
#pragma unroll
    for (int it = 0; it < 10; ++it) {
      int c = wave * 10 + it;
      if (c < 16) {
        int r = c * 8 + srow;
        load_lds16(Ab + (size_t)r * 12288 + k0 + scol, &sA[c * 512]);
      } else {
        int cb = c - 16;
        int r = cb * 8 + srow;
        load_lds16(B + (size_t)r * 12288 + k0 + scol, &sB[cb * 512]);
      }
    }
    __syncthreads();
#pragma unroll
    for (int ks = 0; ks < 2; ++ks) {
      short8 af[4], bfr[6];
#pragma unroll
      for (int i = 0; i < 4; ++i)
        af[i] = *(const short8*)&sA[(wm * 64 + i * 16 + lr) * 64 + ks * 32 + lk];
#pragma unroll
      for (int j = 0; j < 6; ++j)
        bfr[j] = *(const short8*)&sB[(wn * 96 + j * 16 + lr) * 64 + ks * 32 + lk];
#pragma unroll
      for (int i = 0; i < 4; ++i)
#pragma unroll
        for (int j = 0; j < 6; ++j)
          acc[i][j] = __builtin_amdgcn_mfma_f32_16x16x32_bf16(af[i], bfr[j], acc[i][j], 0, 0, 0);
    }
    __syncthreads();
  }
  const int rbase = row0 + wm * 64 + (lane >> 4) * 4;
  const int cbase = wn * 96 + lr;
#pragma unroll
  for (int j = 0; j < 6; ++j) {
    int col = cbase + j * 16;
#pragma unroll
    for (int i = 0; i < 4; ++i)
#pragma unroll
      for (int r = 0; r < 4; ++r) {
        int rw = rbase + i * 16 + r;
        if (SHIFT) {
          if ((rw & 1023) == 1023) continue;  // dropped (next batch's row 0 = bias)
          rw += 1;
        }
        atomicAdd(C + (size_t)rw * 192 + col, acc[i][j][r]);
      }
  }
}

// ---------------------------------------------------------------------------
// Flash-style causal attention: 1-wave blocks for load balance.
// grid (64, H, B); block g covers queries [g*16, g*16+16); heavy-first order.
// lane = (qi, ks): qi = lane&15 query, ks = lane>>4 strides k by 4.
// ---------------------------------------------------------------------------
__global__ __launch_bounds__(64) void attn_kernel(
    const float* __restrict__ q, const float* __restrict__ k,
    const float* __restrict__ v, unsigned short* __restrict__ o) {
  const int g = 63 - (int)blockIdx.x;  // heavy blocks dispatch first
  const int h = blockIdx.y, b = blockIdx.z;
  const int lane = threadIdx.x;
  const int qi = lane & 15, ks = lane >> 4;
  const int qpos = g * 16 + qi;
  const int n = b * 1024 + qpos;
  const float scale = 0.20412414523193154f;  // 1/sqrt(24)
  float qv[24];
  const float* qr = q + (size_t)n * 192 + h * 24;
#pragma unroll
  for (int d = 0; d < 24; ++d) qv[d] = qr[d] * scale;
  float m = -1e30f, l = 0.0f, ov[24] = {};
  const float* kbp = k + (size_t)b * 1024 * 192 + h * 24;
  const float* vbp = v + (size_t)b * 1024 * 192 + h * 24;
  for (int kp = ks; kp <= qpos; kp += 4) {
    const f32x4* kr = (const f32x4*)(kbp + (size_t)kp * 192);
    float s0 = 0.0f, s1 = 0.0f, s2 = 0.0f;  // 3 chains: ~4 deep each
#pragma unroll
    for (int j = 0; j < 2; ++j) {
      f32x4 k0 = kr[j * 3 + 0], k1 = kr[j * 3 + 1], k2 = kr[j * 3 + 2];
#pragma unroll
      for (int e = 0; e < 4; ++e) {
        s0 += qv[(j * 3 + 0) * 4 + e] * k0[e];
        s1 += qv[(j * 3 + 1) * 4 + e] * k1[e];
        s2 += qv[(j * 3 + 2) * 4 + e] * k2[e];
      }
    }
    float s = s0 + s1 + s2;
    float mn = fmaxf(m, s);
    float corr = __expf(m - mn);
    float p = __expf(s - mn);
    const f32x4* vr = (const f32x4*)(vbp + (size_t)kp * 192);
    l = l * corr + p;
#pragma unroll
    for (int j = 0; j < 6; ++j) {
      f32x4 vvv = vr[j];
#pragma unroll
      for (int e = 0; e < 4; ++e) ov[j * 4 + e] = ov[j * 4 + e] * corr + p * vvv[e];
    }
    m = mn;
  }
  // merge the 4 k-slices (lanes qi, qi+16, qi+32, qi+48)
#pragma unroll
  for (int off = 16; off < 64; off <<= 1) {
    float m2 = __shfl_xor(m, off);
    float l2 = __shfl_xor(l, off);
    float mn = fmaxf(m, m2);
    float c1 = __expf(m - mn), c2 = __expf(m2 - mn);
    l = l * c1 + l2 * c2;
#pragma unroll
    for (int d = 0; d < 24; ++d) {
      float o2 = __shfl_xor(ov[d], off);
      ov[d] = ov[d] * c1 + o2 * c2;
    }
    m = mn;
  }
  if (ks == 0) {
    float inv = 1.0f / l;
    unsigned short* orow = o + (size_t)n * 192 + h * 24;
#pragma unroll
    for (int d = 0; d < 24; ++d) orow[d] = f2b(ov[d] * inv);
  }
}

// per-row: p = dot(Dz,x)/(||Dz||+eps)^2 ; x -= p*Dz ; xb = bf16(x)
__global__ __launch_bounds__(256) void proj_update(
    const float* __restrict__ Dz, float* __restrict__ x,
    unsigned short* __restrict__ xb) {
  const int n = blockIdx.x;
  const int tid = threadIdx.x;
  const float* dz = Dz + (size_t)n * 768;
  float* xr = x + (size_t)n * 768;
  float dot = 0.0f, s2 = 0.0f;
  for (int i = tid; i < 768; i += 256) {
    float a = dz[i], c = xr[i];
    dot += a * c;
    s2 += a * a;
  }
#pragma unroll
  for (int o2 = 32; o2; o2 >>= 1) {
    dot += __shfl_down(dot, o2);
    s2 += __shfl_down(s2, o2);
  }
  __shared__ float sd[4], ss[4], sp;
  const int wave = tid >> 6, lane = tid & 63;
  if (lane == 0) { sd[wave] = dot; ss[wave] = s2; }
  __syncthreads();
  if (tid == 0) {
    float Dd = sd[0] + sd[1] + sd[2] + sd[3];
    float S = ss[0] + ss[1] + ss[2] + ss[3];
    float nrm = sqrtf(S) + 1e-6f;
    sp = Dd / (nrm * nrm);
  }
  __syncthreads();
  float p = sp;
  for (int i = tid; i < 768; i += 256) {
    float nx = xr[i] - p * dz[i];
    xr[i] = nx;
    xb[(size_t)n * 768 + i] = f2b(nx);
  }
}

DEVFN int sanitize(int v) { return (v & 0x8000) ? 0 : v; }  // -0/neg codes -> 0

// top-32 of z_novel row (bf16 codes nonneg => int order = value order);
// emits 32 (idx,val) pairs per row (slot order arbitrary).
__global__ __launch_bounds__(256) void topk_rows(
    const unsigned short* __restrict__ zbuf, int* __restrict__ idxo,
    float* __restrict__ valo) {
  const int n = blockIdx.x;
  const int b = n >> 10;
  const int tid = threadIdx.x;
  const int wave = tid >> 6, lane = tid & 63;
  const uint4v* zr = (const uint4v*)(zbuf + (size_t)(n + b + 1) * 12288);
  uint4v pk[6];
#pragma unroll
  for (int j = 0; j < 6; ++j) pk[j] = zr[tid * 6 + j];
  __shared__ int swsum[4];
  __shared__ int seq[256];
  __shared__ int spcnt;
  int lo = 0, hi = 0x7F7F;
  while (lo < hi) {
    int mid = (lo + hi) >> 1;
    int c = 0;
#pragma unroll
    for (int j = 0; j < 6; ++j)
#pragma unroll
      for (int e = 0; e < 4; ++e) {
        unsigned int u = pk[j][e];
        c += (sanitize((int)(u & 0xffffu)) > mid) + (sanitize((int)(u >> 16)) > mid);
      }
#pragma unroll
    for (int o2 = 32; o2; o2 >>= 1) c += __shfl_down(c, o2);
    if (lane == 0) swsum[wave] = c;
    __syncthreads();
    int total = swsum[0] + swsum[1] + swsum[2] + swsum[3];
    __syncthreads();
    if (total < 32) hi = mid; else lo = mid + 1;
  }
  const int T = lo;
  int cgt = 0, ceq = 0;
#pragma unroll
  for (int j = 0; j < 6; ++j)
#pragma unroll
    for (int e = 0; e < 4; ++e) {
      unsigned int u = pk[j][e];
      int v0 = sanitize((int)(u & 0xffffu)), v1 = sanitize((int)(u >> 16));
      cgt += (v0 > T) + (v1 > T);
      ceq += (v0 == T) + (v1 == T);
    }
  int cg = cgt;
#pragma unroll
  for (int o2 = 32; o2; o2 >>= 1) cg += __shfl_down(cg, o2);
  if (lane == 0) swsum[wave] = cg;
  seq[tid] = ceq;
  if (tid == 0) spcnt = 0;
  __syncthreads();
  const int total_gt = swsum[0] + swsum[1] + swsum[2] + swsum[3];
  for (int o2 = 1; o2 < 256; o2 <<= 1) {
    int vv = (tid >= o2) ? seq[tid - o2] : 0;
    __syncthreads();
    seq[tid] += vv;
    __syncthreads();
  }
  const int quota = 32 - total_gt;
  int rank = seq[tid] - ceq;
  int* irow = idxo + (size_t)n * 32;
  float* vrow = valo + (size_t)n * 32;
#pragma unroll
  for (int j = 0; j < 6; ++j)
#pragma unroll
    for (int e = 0; e < 4; ++e) {
      unsigned int u = pk[j][e];
#pragma unroll
      for (int hf = 0; hf < 2; ++hf) {
        int v = sanitize(hf ? (int)(u >> 16) : (int)(u & 0xffffu));
        bool kp = false;
        if (v > T) kp = true;
        else if (v == T) { if (rank < quota) kp = true; ++rank; }
        if (kp) {
          int pos = atomicAdd(&spcnt, 1);
          irow[pos] = tid * 48 + j * 8 + e * 2 + hf;
          vrow[pos] = b2f((unsigned short)v);
        }
      }
    }
}

// out = x_input - x_final + sum_j val_j * D[idx_j,:]   (f32 in, f32 out)
__global__ __launch_bounds__(256) void sparse_recons(
    const int* __restrict__ idxo, const float* __restrict__ valo,
    const float* __restrict__ x, const float* __restrict__ xin,
    const float* __restrict__ D, float* __restrict__ out) {
  const int n = blockIdx.x;
  const int t = threadIdx.x;
  __shared__ int sidx[32];
  __shared__ float sval[32];
  if (t < 32) { sidx[t] = idxo[(size_t)n * 32 + t]; sval[t] = valo[(size_t)n * 32 + t]; }
  __syncthreads();
  float acc[3];
#pragma unroll
  for (int u = 0; u < 3; ++u) {
    size_t i = (size_t)n * 768 + t + u * 256;
    acc[u] = xin[i] - x[i];
  }
  for (int j = 0; j < 32; ++j) {
    size_t base = (size_t)sidx[j] * 768;
    float vj = sval[j];
#pragma unroll
    for (int u = 0; u < 3; ++u) acc[u] += vj * D[base + t + u * 256];
  }
#pragma unroll
  for (int u = 0; u < 3; ++u) out[(size_t)n * 768 + t + u * 256] = acc[u];
}

// ===========================================================================
extern "C" void kernel_launch(void* const* d_in, const int* in_sizes, int n_in,
                              void* d_out, int out_size, void* d_ws, size_t ws_size,
                              hipStream_t stream) {
  (void)in_sizes; (void)n_in;
  const float* xin  = (const float*)d_in[0];
  const float* D    = (const float*)d_in[1];
  const float* bvec = (const float*)d_in[2];
  const float* Wq   = (const float*)d_in[3];
  const float* bq   = (const float*)d_in[4];
  const float* Wk   = (const float*)d_in[5];
  const float* bk   = (const float*)d_in[6];
  const float* Wv   = (const float*)d_in[7];
  const float* bv   = (const float*)d_in[8];
  const float* Wo   = (const float*)d_in[9];
  const float* bo   = (const float*)d_in[10];
  const float LAM = 1.0f / 3072.0f;

  char* ws = (char*)d_ws;
  size_t off = 0;
  auto alloc = [&](size_t bytes) {
    void* p = ws + off;
    off += (bytes + 255) & ~(size_t)255;
    return p;
  };
  unsigned short* zbuf = (unsigned short*)alloc((size_t)4 * 1025 * 12288 * 2);
  unsigned short* zpred_ = zbuf;  // alias: lifetimes disjoint
  float* x           = (float*)alloc((size_t)4096 * 768 * 4);
  unsigned short* xb = (unsigned short*)alloc((size_t)4096 * 768 * 2);
  float* qb  = (float*)alloc((size_t)4096 * 192 * 4);
  float* kb  = (float*)alloc((size_t)4096 * 192 * 4);
  float* vb  = (float*)alloc((size_t)4096 * 192 * 4);
  unsigned short* ob = (unsigned short*)alloc((size_t)4096 * 192 * 2);
  float* Dz  = (float*)alloc((size_t)4096 * 768 * 4);
  int* idxo  = (int*)alloc((size_t)4096 * 32 * 4);
  float* valo = (float*)alloc((size_t)4096 * 32 * 4);
  const size_t WQKV = (size_t)192 * 12288;   // per (layer, weight)
  unsigned short* WqkvT = (unsigned short*)alloc((size_t)6 * WQKV * 2);
  unsigned short* WoT   = (unsigned short*)alloc((size_t)2 * 12288 * 192 * 2);
  unsigned short* Dbt   = (unsigned short*)alloc((size_t)12288 * 768 * 2);
  unsigned short* Dt    = (unsigned short*)alloc((size_t)768 * 12288 * 2);
  const size_t NEED = off;  // ~219.8 MB (confirmed fitting in R5)

  if (ws_size < NEED) {  // safety net (should never fire; ws >= NEED verified)
    fill_out_zero<<<(out_size + 255) / 256, 256, 0, stream>>>((float*)d_out, out_size);
    return;
  }

  init_x<<<12288, 256, 0, stream>>>(xin, bvec, x, xb);
  conv_f2b<<<9216, 256, 0, stream>>>(D, Dbt);
  transpose_f2b<<<dim3(384, 24), 256, 0, stream>>>(D, Dt, 12288, 768);
  for (int l = 0; l < 2; ++l) {
    transpose_f2b<<<dim3(384, 6), 256, 0, stream>>>(
        Wq + (size_t)l * 12288 * 192, WqkvT + (size_t)(l * 3 + 0) * WQKV, 12288, 192);
    transpose_f2b<<<dim3(384, 6), 256, 0, stream>>>(
        Wk + (size_t)l * 12288 * 192, WqkvT + (size_t)(l * 3 + 1) * WQKV, 12288, 192);
    transpose_f2b<<<dim3(384, 6), 256, 0, stream>>>(
        Wv + (size_t)l * 12288 * 192, WqkvT + (size_t)(l * 3 + 2) * WQKV, 12288, 192);
    transpose_f2b<<<dim3(6, 384), 256, 0, stream>>>(
        Wo + (size_t)l * 192 * 12288, WoT + (size_t)l * 12288 * 192, 192, 12288);
  }

  for (int l = 0; l < 2; ++l) {
    // z_in = relu(LAM * x @ D^T) -> zbuf shifted rows [b*1025+1 ..]
    gemm_bt2<unsigned short, true, 1, false, false><<<dim3(32, 96), 256, 0, stream>>>(
        xb, Dbt, zbuf, nullptr, 768, 12288, LAM);
    // q/k/v from the SAME z_in view; k/v stored row-shifted (z_ctx shift).
    // Bias prefill doubles as the zero-context row (in-batch row 0) for k/v.
    fill_bias<<<3072, 256, 0, stream>>>(qb, bq + (size_t)l * 192, 192);
    fill_bias<<<3072, 256, 0, stream>>>(kb, bk + (size_t)l * 192, 192);
    fill_bias<<<3072, 256, 0, stream>>>(vb, bv + (size_t)l * 192, 192);
    gemm_qkv<0><<<dim3(32, 8), 256, 0, stream>>>(zbuf, WqkvT + (size_t)(l * 3 + 0) * WQKV, qb);
    gemm_qkv<1><<<dim3(32, 8), 256, 0, stream>>>(zbuf, WqkvT + (size_t)(l * 3 + 1) * WQKV, kb);
    gemm_qkv<1><<<dim3(32, 8), 256, 0, stream>>>(zbuf, WqkvT + (size_t)(l * 3 + 2) * WQKV, vb);
    attn_kernel<<<dim3(64, 8, 4), 64, 0, stream>>>(qb, kb, vb, ob);
    // z_pred_ = relu(o @ Wo + bo) -> zpred_ (aliases zbuf; z_in dead)
    gemm_bt2<unsigned short, true, 0, true, false><<<dim3(32, 96), 256, 0, stream>>>(
        ob, WoT + (size_t)l * 12288 * 192, zpred_, bo + (size_t)l * 12288, 192, 12288, 1.0f);
    // Dz = z_pred_ @ D  (split-K=2, atomic into zero-prefilled f32)
    fill_bias<<<12288, 256, 0, stream>>>(Dz, nullptr, 768);
    gemm_bt2<float, false, 0, false, true><<<dim3(32, 6, 2), 256, 0, stream>>>(
        zpred_, Dt, Dz, nullptr, 12288, 768, 1.0f);
    proj_update<<<4096, 256, 0, stream>>>(Dz, x, xb);
  }
  // z_novel = relu(LAM * x @ D^T) -> zbuf shifted rows
  gemm_bt2<unsigned short, true, 1, false, false><<<dim3(32, 96), 256, 0, stream>>>(
      xb, Dbt, zbuf, nullptr, 768, 12288, LAM);
  topk_rows<<<4096, 256, 0, stream>>>(zbuf, idxo, valo);
  sparse_recons<<<4096, 256, 0, stream>>>(idxo, valo, x, xin, D, (float*)d_out);
}

// Round 7
// 1727.287 us; speedup vs baseline: 1.1512x; 1.1512x over previous
//
#include <hip/hip_runtime.h>
#include <hip/hip_bf16.h>

typedef __attribute__((ext_vector_type(4))) float f32x4;
typedef __attribute__((ext_vector_type(8))) short short8;
typedef __attribute__((ext_vector_type(8))) unsigned short ushort8;
typedef __attribute__((ext_vector_type(4))) unsigned short ushort4v;
typedef __attribute__((ext_vector_type(4))) unsigned int uint4v;

#define DEVFN __device__ __forceinline__

DEVFN float b2f(unsigned short u) { return __uint_as_float(((unsigned)u) << 16); }
DEVFN unsigned short f2b(float f) {
  __hip_bfloat16 h = __float2bfloat16(f);
  return __builtin_bit_cast(unsigned short, h);
}

DEVFN void load_lds16(const void* g, void* l) {
  __builtin_amdgcn_global_load_lds(
      (const __attribute__((address_space(1))) unsigned int*)g,
      (__attribute__((address_space(3))) unsigned int*)l, 16, 0, 0);
}

// ===========================================================================

__global__ void fill_out_zero(float* o, int n) {
  int i = blockIdx.x * 256 + threadIdx.x;
  if (i < n) o[i] = 0.0f;
}

__global__ __launch_bounds__(256) void init_x(
    const float* __restrict__ xin, const float* __restrict__ bvec,
    float* __restrict__ x, unsigned short* __restrict__ xb) {
  size_t i = (size_t)blockIdx.x * 256 + threadIdx.x;
  int col = (int)(i % 768);
  float v = xin[i] - bvec[col];
  x[i] = v;
  xb[i] = f2b(v);
}

// buf[i] = bias[i % ld] (or 0 if bias null)
__global__ __launch_bounds__(256) void fill_bias(
    float* __restrict__ buf, const float* __restrict__ bias, int ld) {
  size_t i = (size_t)blockIdx.x * 256 + threadIdx.x;
  buf[i] = bias ? bias[(int)(i % ld)] : 0.0f;
}

// f32 -> bf16 straight convert, 4 elems/thread (n must be /1024)
__global__ __launch_bounds__(256) void conv_f2b(
    const float* __restrict__ in, unsigned short* __restrict__ out) {
  size_t i = ((size_t)blockIdx.x * 256 + threadIdx.x) * 4;
  f32x4 v = *(const f32x4*)(in + i);
  ushort4v w;
#pragma unroll
  for (int e = 0; e < 4; ++e) w[e] = f2b(v[e]);
  *(ushort4v*)(out + i) = w;
}

// out[c][r] = bf16(in[r][c]); R,C multiples of 32; grid (R/32, C/32)
__global__ __launch_bounds__(256) void transpose_f2b(
    const float* __restrict__ in, unsigned short* __restrict__ out,
    int R, int C) {
  __shared__ float tile[32][33];
  int r0 = blockIdx.x * 32, c0 = blockIdx.y * 32;
  int tx = threadIdx.x & 31, ty = threadIdx.x >> 5;
#pragma unroll
  for (int i = 0; i < 4; ++i)
    tile[ty + i * 8][tx] = in[(size_t)(r0 + ty + i * 8) * C + c0 + tx];
  __syncthreads();
#pragma unroll
  for (int i = 0; i < 4; ++i)
    out[(size_t)(c0 + ty + i * 8) * R + r0 + tx] = f2b(tile[tx][ty + i * 8]);
}

// ---------------------------------------------------------------------------
// gemm_bt2: C[M,N] = epi(alpha * A[M,K] . B[N,K]^T + bias)  both bf16 K-major.
// 128x128 tile, BK=64, global_load_lds staging (conflict-free).
// SC=1: C rows shifted per batch (z storage [b][1+1024][W]).
// ---------------------------------------------------------------------------
template <typename CT, bool RELU, int SC, bool BIAS, bool SPLITK>
__global__ __launch_bounds__(256) void gemm_bt2(
    const unsigned short* __restrict__ A, const unsigned short* __restrict__ B,
    CT* __restrict__ C, const float* __restrict__ bias,
    int K, int ldc, float alpha) {
  __shared__ unsigned short sA[128 * 64];
  __shared__ unsigned short sB[128 * 64];
  const int tid = threadIdx.x;
  const int wave = tid >> 6, lane = tid & 63;
  const int row0 = blockIdx.x * 128, col0 = blockIdx.y * 128;
  const unsigned short* Ab = A + (size_t)row0 * K;
  const unsigned short* Bb = B + (size_t)col0 * K;
  const int srow = lane >> 3;
  const int scol = (lane & 7) * 8;
  const int wm = wave & 1, wn = wave >> 1;
  const int lr = lane & 15;
  const int lk = (lane >> 4) * 8;
  const int klen = SPLITK ? (K / (int)gridDim.z) : K;
  const int kbeg = SPLITK ? (int)blockIdx.z * klen : 0;
  f32x4 acc[4][4] = {};
  for (int k0 = kbeg; k0 < kbeg + klen; k0 += 64) {
#pragma unroll
    for (int it = 0; it < 4; ++it) {
      int chunk = wave * 4 + it;
      int r = chunk * 8 + srow;
      load_lds16(Ab + (size_t)r * K + k0 + scol, &sA[chunk * 512]);
      load_lds16(Bb + (size_t)r * K + k0 + scol, &sB[chunk * 512]);
    }
    __syncthreads();
#pragma unroll
    for (int ks = 0; ks < 2; ++ks) {
      short8 af[4], bfr[4];
#pragma unroll
      for (int i = 0; i < 4; ++i)
        af[i] = *(const short8*)&sA[(wm * 64 + i * 16 + lr) * 64 + ks * 32 + lk];
#pragma unroll
      for (int i = 0; i < 4; ++i)
        bfr[i] = *(const short8*)&sB[(wn * 64 + i * 16 + lr) * 64 + ks * 32 + lk];
#pragma unroll
      for (int i = 0; i < 4; ++i)
#pragma unroll
        for (int j = 0; j < 4; ++j)
          acc[i][j] = __builtin_amdgcn_mfma_f32_16x16x32_bf16(af[i], bfr[j], acc[i][j], 0, 0, 0);
    }
    __syncthreads();
  }
  const int rc = (SC == 0) ? 0 : ((row0 >> 10) + 1);
  const int rbase = row0 + rc + wm * 64 + (lane >> 4) * 4;
  const int cbase = col0 + wn * 64 + lr;
#pragma unroll
  for (int j = 0; j < 4; ++j) {
    int col = cbase + j * 16;
    float bv = BIAS ? bias[col] : 0.0f;
#pragma unroll
    for (int i = 0; i < 4; ++i) {
#pragma unroll
      for (int r = 0; r < 4; ++r) {
        float vv = acc[i][j][r] * alpha;
        size_t off = (size_t)(rbase + i * 16 + r) * ldc + col;
        if constexpr (SPLITK) {
          atomicAdd((float*)C + off, vv);
        } else {
          vv += bv;
          if (RELU) vv = fmaxf(vv, 0.0f);
          if constexpr (sizeof(CT) == 2) ((unsigned short*)C)[off] = f2b(vv);
          else C[off] = vv;
        }
      }
    }
  }
}

// ---------------------------------------------------------------------------
// gemm_qkv: C[4096,192] (f32, atomic) += A_zin . B[192,12288]^T
// BM=128, BN=192, BK=64, waves 2x2 (64x96 each); grid (32 rows, 8 k-splits).
// A is always the z_in view. SHIFT=1 (k/v): store row t -> t+1 within batch,
// dropping in-batch row 1023 (z_ctx shift done at write time).
// ---------------------------------------------------------------------------
template <int SHIFT>
__global__ __launch_bounds__(256) void gemm_qkv(
    const unsigned short* __restrict__ A, const unsigned short* __restrict__ B,
    float* __restrict__ C) {
  __shared__ unsigned short sA[128 * 64];   // 16 KB
  __shared__ unsigned short sB[192 * 64];   // 24 KB
  const int tid = threadIdx.x;
  const int wave = tid >> 6, lane = tid & 63;
  const int row0 = blockIdx.x * 128;
  const int ra = (row0 >> 10) + 1;          // z_in view
  const unsigned short* Ab = A + (size_t)(row0 + ra) * 12288;
  const int srow = lane >> 3;
  const int scol = (lane & 7) * 8;
  const int wm = wave & 1, wn = wave >> 1;
  const int lr = lane & 15;
  const int lk = (lane >> 4) * 8;
  const int kbeg = (int)blockIdx.y * 1536;  // 12288/8
  f32x4 acc[4][6] = {};
  for (int k0 = kbeg; k0 < kbeg + 1536; k0 += 64) {
    // 40 chunks of 8 rows: 0..15 = A, 16..39 = B; 10 per wave
#pragma unroll
    for (int it = 0; it < 10; ++it) {
      int c = wave * 10 + it;
      if (c < 16) {
        int r = c * 8 + srow;
        load_lds16(Ab + (size_t)r * 12288 + k0 + scol, &sA[c * 512]);
      } else {
        int cb = c - 16;
        int r = cb * 8 + srow;
        load_lds16(B + (size_t)r * 12288 + k0 + scol, &sB[cb * 512]);
      }
    }
    __syncthreads();
#pragma unroll
    for (int ks = 0; ks < 2; ++ks) {
      short8 af[4], bfr[6];
#pragma unroll
      for (int i = 0; i < 4; ++i)
        af[i] = *(const short8*)&sA[(wm * 64 + i * 16 + lr) * 64 + ks * 32 + lk];
#pragma unroll
      for (int j = 0; j < 6; ++j)
        bfr[j] = *(const short8*)&sB[(wn * 96 + j * 16 + lr) * 64 + ks * 32 + lk];
#pragma unroll
      for (int i = 0; i < 4; ++i)
#pragma unroll
        for (int j = 0; j < 6; ++j)
          acc[i][j] = __builtin_amdgcn_mfma_f32_16x16x32_bf16(af[i], bfr[j], acc[i][j], 0, 0, 0);
    }
    __syncthreads();
  }
  const int rbase = row0 + wm * 64 + (lane >> 4) * 4;
  const int cbase = wn * 96 + lr;
#pragma unroll
  for (int j = 0; j < 6; ++j) {
    int col = cbase + j * 16;
#pragma unroll
    for (int i = 0; i < 4; ++i)
#pragma unroll
      for (int r = 0; r < 4; ++r) {
        int rw = rbase + i * 16 + r;
        if (SHIFT) {
          if ((rw & 1023) == 1023) continue;  // dropped (next batch's row 0 = bias)
          rw += 1;
        }
        atomicAdd(C + (size_t)rw * 192 + col, acc[i][j][r]);
      }
  }
}

// ---------------------------------------------------------------------------
// Attention, two-pass flash-decode.
// Pass 1: task = (b,h,qgroup16,kchunk128). 9216 uniform wave-tasks, 4/block.
//   Per (b,h): 288 tasks; group g8=qg>>3 has 8 qgroups x (g8+1) chunks,
//   cumulative offset 4*g8*(g8+1). Partials P[task][qi] = {m, l, ov[24]}
//   (stride 28 floats) land in scratch (dead zbuf region).
// Pass 2: merge <=8 chunks per query; thread = (query; h,d).
// ---------------------------------------------------------------------------
__global__ __launch_bounds__(256) void attn_pass1(
    const float* __restrict__ q, const float* __restrict__ k,
    const float* __restrict__ v, float* __restrict__ P) {
  const int wave = threadIdx.x >> 6, lane = threadIdx.x & 63;
  const int task = (int)blockIdx.x * 4 + wave;  // 0..9215
  const int bh = task / 288, t = task % 288;
  const int b = bh >> 3, h = bh & 7;
  int g8 = 0;
  while (4 * (g8 + 1) * (g8 + 2) <= t) ++g8;
  const int r = t - 4 * g8 * (g8 + 1);
  const int qg = g8 * 8 + r / (g8 + 1);
  const int chunk = r % (g8 + 1);
  const int qi = lane & 15, ks = lane >> 4;
  const int qpos = qg * 16 + qi;
  const int n = b * 1024 + qpos;
  const float scale = 0.20412414523193154f;  // 1/sqrt(24)
  float qv[24];
  const float* qr = q + (size_t)n * 192 + h * 24;
#pragma unroll
  for (int d = 0; d < 24; ++d) qv[d] = qr[d] * scale;
  float m = -1e30f, l = 0.0f, ov[24] = {};
  const float* kbp = k + (size_t)b * 1024 * 192 + h * 24;
  const float* vbp = v + (size_t)b * 1024 * 192 + h * 24;
  const int kend = min(qpos, chunk * 128 + 127);
  for (int kp = chunk * 128 + ks; kp <= kend; kp += 4) {
    const f32x4* kr = (const f32x4*)(kbp + (size_t)kp * 192);
    float s0 = 0.0f, s1 = 0.0f, s2 = 0.0f;
#pragma unroll
    for (int j = 0; j < 2; ++j) {
      f32x4 k0 = kr[j * 3 + 0], k1 = kr[j * 3 + 1], k2 = kr[j * 3 + 2];
#pragma unroll
      for (int e = 0; e < 4; ++e) {
        s0 += qv[(j * 3 + 0) * 4 + e] * k0[e];
        s1 += qv[(j * 3 + 1) * 4 + e] * k1[e];
        s2 += qv[(j * 3 + 2) * 4 + e] * k2[e];
      }
    }
    float s = s0 + s1 + s2;
    float mn = fmaxf(m, s);
    float corr = __expf(m - mn);
    float p = __expf(s - mn);
    const f32x4* vr = (const f32x4*)(vbp + (size_t)kp * 192);
    l = l * corr + p;
#pragma unroll
    for (int j = 0; j < 6; ++j) {
      f32x4 vvv = vr[j];
#pragma unroll
      for (int e = 0; e < 4; ++e) ov[j * 4 + e] = ov[j * 4 + e] * corr + p * vvv[e];
    }
    m = mn;
  }
  // merge the 4 k-slices (lanes qi, qi+16, qi+32, qi+48)
#pragma unroll
  for (int off = 16; off < 64; off <<= 1) {
    float m2 = __shfl_xor(m, off);
    float l2 = __shfl_xor(l, off);
    float mn = fmaxf(m, m2);
    float c1 = __expf(m - mn), c2 = __expf(m2 - mn);
    l = l * c1 + l2 * c2;
#pragma unroll
    for (int d = 0; d < 24; ++d) {
      float o2 = __shfl_xor(ov[d], off);
      ov[d] = ov[d] * c1 + o2 * c2;
    }
    m = mn;
  }
  if (ks == 0) {
    float* pr = P + ((size_t)task * 16 + qi) * 28;
    pr[0] = m;
    pr[1] = l;
#pragma unroll
    for (int d = 0; d < 24; ++d) pr[2 + d] = ov[d];
  }
}

__global__ __launch_bounds__(192) void attn_merge(
    const float* __restrict__ P, unsigned short* __restrict__ o) {
  const int n = blockIdx.x;            // 0..4095
  const int tid = threadIdx.x;
  const int h = tid / 24, d = tid - h * 24;
  const int b = n >> 10, qpos = n & 1023;
  const int qg = qpos >> 4, qi = qpos & 15;
  const int g8 = qg >> 3;
  const int nch = g8 + 1;              // == qpos/128 + 1 for all qi in group
  const int bh = b * 8 + h;
  const int base = bh * 288 + 4 * g8 * (g8 + 1) + (qg - g8 * 8) * (g8 + 1);
  float M = -1e30f;
  for (int c = 0; c < nch; ++c)
    M = fmaxf(M, P[((size_t)(base + c) * 16 + qi) * 28]);
  float L = 0.0f, OV = 0.0f;
  for (int c = 0; c < nch; ++c) {
    const float* pr = P + ((size_t)(base + c) * 16 + qi) * 28;
    float w = __expf(pr[0] - M);
    L += pr[1] * w;
    OV += pr[2 + d] * w;
  }
  o[(size_t)n * 192 + h * 24 + d] = f2b(OV / L);
}

// per-row: p = dot(Dz,x)/(||Dz||+eps)^2 ; x -= p*Dz ; xb = bf16(x)
__global__ __launch_bounds__(256) void proj_update(
    const float* __restrict__ Dz, float* __restrict__ x,
    unsigned short* __restrict__ xb) {
  const int n = blockIdx.x;
  const int tid = threadIdx.x;
  const float* dz = Dz + (size_t)n * 768;
  float* xr = x + (size_t)n * 768;
  float dot = 0.0f, s2 = 0.0f;
  for (int i = tid; i < 768; i += 256) {
    float a = dz[i], c = xr[i];
    dot += a * c;
    s2 += a * a;
  }
#pragma unroll
  for (int o2 = 32; o2; o2 >>= 1) {
    dot += __shfl_down(dot, o2);
    s2 += __shfl_down(s2, o2);
  }
  __shared__ float sd[4], ss[4], sp;
  const int wave = tid >> 6, lane = tid & 63;
  if (lane == 0) { sd[wave] = dot; ss[wave] = s2; }
  __syncthreads();
  if (tid == 0) {
    float Dd = sd[0] + sd[1] + sd[2] + sd[3];
    float S = ss[0] + ss[1] + ss[2] + ss[3];
    float nrm = sqrtf(S) + 1e-6f;
    sp = Dd / (nrm * nrm);
  }
  __syncthreads();
  float p = sp;
  for (int i = tid; i < 768; i += 256) {
    float nx = xr[i] - p * dz[i];
    xr[i] = nx;
    xb[(size_t)n * 768 + i] = f2b(nx);
  }
}

DEVFN int sanitize(int v) { return (v & 0x8000) ? 0 : v; }  // -0/neg codes -> 0

// top-32 of z_novel row (bf16 codes nonneg => int order = value order);
// emits 32 (idx,val) pairs per row (slot order arbitrary).
__global__ __launch_bounds__(256) void topk_rows(
    const unsigned short* __restrict__ zbuf, int* __restrict__ idxo,
    float* __restrict__ valo) {
  const int n = blockIdx.x;
  const int b = n >> 10;
  const int tid = threadIdx.x;
  const int wave = tid >> 6, lane = tid & 63;
  const uint4v* zr = (const uint4v*)(zbuf + (size_t)(n + b + 1) * 12288);
  uint4v pk[6];
#pragma unroll
  for (int j = 0; j < 6; ++j) pk[j] = zr[tid * 6 + j];
  __shared__ int swsum[4];
  __shared__ int seq[256];
  __shared__ int spcnt;
  int lo = 0, hi = 0x7F7F;
  while (lo < hi) {
    int mid = (lo + hi) >> 1;
    int c = 0;
#pragma unroll
    for (int j = 0; j < 6; ++j)
#pragma unroll
      for (int e = 0; e < 4; ++e) {
        unsigned int u = pk[j][e];
        c += (sanitize((int)(u & 0xffffu)) > mid) + (sanitize((int)(u >> 16)) > mid);
      }
#pragma unroll
    for (int o2 = 32; o2; o2 >>= 1) c += __shfl_down(c, o2);
    if (lane == 0) swsum[wave] = c;
    __syncthreads();
    int total = swsum[0] + swsum[1] + swsum[2] + swsum[3];
    __syncthreads();
    if (total < 32) hi = mid; else lo = mid + 1;
  }
  const int T = lo;
  int cgt = 0, ceq = 0;
#pragma unroll
  for (int j = 0; j < 6; ++j)
#pragma unroll
    for (int e = 0; e < 4; ++e) {
      unsigned int u = pk[j][e];
      int v0 = sanitize((int)(u & 0xffffu)), v1 = sanitize((int)(u >> 16));
      cgt += (v0 > T) + (v1 > T);
      ceq += (v0 == T) + (v1 == T);
    }
  int cg = cgt;
#pragma unroll
  for (int o2 = 32; o2; o2 >>= 1) cg += __shfl_down(cg, o2);
  if (lane == 0) swsum[wave] = cg;
  seq[tid] = ceq;
  if (tid == 0) spcnt = 0;
  __syncthreads();
  const int total_gt = swsum[0] + swsum[1] + swsum[2] + swsum[3];
  for (int o2 = 1; o2 < 256; o2 <<= 1) {
    int vv = (tid >= o2) ? seq[tid - o2] : 0;
    __syncthreads();
    seq[tid] += vv;
    __syncthreads();
  }
  const int quota = 32 - total_gt;
  int rank = seq[tid] - ceq;
  int* irow = idxo + (size_t)n * 32;
  float* vrow = valo + (size_t)n * 32;
#pragma unroll
  for (int j = 0; j < 6; ++j)
#pragma unroll
    for (int e = 0; e < 4; ++e) {
      unsigned int u = pk[j][e];
#pragma unroll
      for (int hf = 0; hf < 2; ++hf) {
        int v = sanitize(hf ? (int)(u >> 16) : (int)(u & 0xffffu));
        bool kp = false;
        if (v > T) kp = true;
        else if (v == T) { if (rank < quota) kp = true; ++rank; }
        if (kp) {
          int pos = atomicAdd(&spcnt, 1);
          irow[pos] = tid * 48 + j * 8 + e * 2 + hf;
          vrow[pos] = b2f((unsigned short)v);
        }
      }
    }
}

// out = x_input - x_final + sum_j val_j * D[idx_j,:]   (f32 in, f32 out)
__global__ __launch_bounds__(256) void sparse_recons(
    const int* __restrict__ idxo, const float* __restrict__ valo,
    const float* __restrict__ x, const float* __restrict__ xin,
    const float* __restrict__ D, float* __restrict__ out) {
  const int n = blockIdx.x;
  const int t = threadIdx.x;
  __shared__ int sidx[32];
  __shared__ float sval[32];
  if (t < 32) { sidx[t] = idxo[(size_t)n * 32 + t]; sval[t] = valo[(size_t)n * 32 + t]; }
  __syncthreads();
  float acc[3];
#pragma unroll
  for (int u = 0; u < 3; ++u) {
    size_t i = (size_t)n * 768 + t + u * 256;
    acc[u] = xin[i] - x[i];
  }
  for (int j = 0; j < 32; ++j) {
    size_t base = (size_t)sidx[j] * 768;
    float vj = sval[j];
#pragma unroll
    for (int u = 0; u < 3; ++u) acc[u] += vj * D[base + t + u * 256];
  }
#pragma unroll
  for (int u = 0; u < 3; ++u) out[(size_t)n * 768 + t + u * 256] = acc[u];
}

// ===========================================================================
extern "C" void kernel_launch(void* const* d_in, const int* in_sizes, int n_in,
                              void* d_out, int out_size, void* d_ws, size_t ws_size,
                              hipStream_t stream) {
  (void)in_sizes; (void)n_in;
  const float* xin  = (const float*)d_in[0];
  const float* D    = (const float*)d_in[1];
  const float* bvec = (const float*)d_in[2];
  const float* Wq   = (const float*)d_in[3];
  const float* bq   = (const float*)d_in[4];
  const float* Wk   = (const float*)d_in[5];
  const float* bk   = (const float*)d_in[6];
  const float* Wv   = (const float*)d_in[7];
  const float* bv   = (const float*)d_in[8];
  const float* Wo   = (const float*)d_in[9];
  const float* bo   = (const float*)d_in[10];
  const float LAM = 1.0f / 3072.0f;

  char* ws = (char*)d_ws;
  size_t off = 0;
  auto alloc = [&](size_t bytes) {
    void* p = ws + off;
    off += (bytes + 255) & ~(size_t)255;
    return p;
  };
  unsigned short* zbuf = (unsigned short*)alloc((size_t)4 * 1025 * 12288 * 2);
  unsigned short* zpred_ = zbuf;  // alias: lifetimes disjoint
  float* attnP = (float*)zbuf;    // alias: partials live between qkv and Wo GEMMs
  float* x           = (float*)alloc((size_t)4096 * 768 * 4);
  unsigned short* xb = (unsigned short*)alloc((size_t)4096 * 768 * 2);
  float* qb  = (float*)alloc((size_t)4096 * 192 * 4);
  float* kb  = (float*)alloc((size_t)4096 * 192 * 4);
  float* vb  = (float*)alloc((size_t)4096 * 192 * 4);
  unsigned short* ob = (unsigned short*)alloc((size_t)4096 * 192 * 2);
  float* Dz  = (float*)alloc((size_t)4096 * 768 * 4);
  int* idxo  = (int*)alloc((size_t)4096 * 32 * 4);
  float* valo = (float*)alloc((size_t)4096 * 32 * 4);
  const size_t WQKV = (size_t)192 * 12288;   // per (layer, weight)
  unsigned short* WqkvT = (unsigned short*)alloc((size_t)6 * WQKV * 2);
  unsigned short* WoT   = (unsigned short*)alloc((size_t)2 * 12288 * 192 * 2);
  unsigned short* Dbt   = (unsigned short*)alloc((size_t)12288 * 768 * 2);
  unsigned short* Dt    = (unsigned short*)alloc((size_t)768 * 12288 * 2);
  const size_t NEED = off;  // ~219.8 MB (confirmed fitting in R5/R6)

  if (ws_size < NEED) {  // safety net (should never fire)
    fill_out_zero<<<(out_size + 255) / 256, 256, 0, stream>>>((float*)d_out, out_size);
    return;
  }

  init_x<<<12288, 256, 0, stream>>>(xin, bvec, x, xb);
  conv_f2b<<<9216, 256, 0, stream>>>(D, Dbt);
  transpose_f2b<<<dim3(384, 24), 256, 0, stream>>>(D, Dt, 12288, 768);
  for (int l = 0; l < 2; ++l) {
    transpose_f2b<<<dim3(384, 6), 256, 0, stream>>>(
        Wq + (size_t)l * 12288 * 192, WqkvT + (size_t)(l * 3 + 0) * WQKV, 12288, 192);
    transpose_f2b<<<dim3(384, 6), 256, 0, stream>>>(
        Wk + (size_t)l * 12288 * 192, WqkvT + (size_t)(l * 3 + 1) * WQKV, 12288, 192);
    transpose_f2b<<<dim3(384, 6), 256, 0, stream>>>(
        Wv + (size_t)l * 12288 * 192, WqkvT + (size_t)(l * 3 + 2) * WQKV, 12288, 192);
    transpose_f2b<<<dim3(6, 384), 256, 0, stream>>>(
        Wo + (size_t)l * 192 * 12288, WoT + (size_t)l * 12288 * 192, 192, 12288);
  }

  for (int l = 0; l < 2; ++l) {
    // z_in = relu(LAM * x @ D^T) -> zbuf shifted rows [b*1025+1 ..]
    gemm_bt2<unsigned short, true, 1, false, false><<<dim3(32, 96), 256, 0, stream>>>(
        xb, Dbt, zbuf, nullptr, 768, 12288, LAM);
    // q/k/v from the SAME z_in view; k/v stored row-shifted (z_ctx shift).
    // Bias prefill doubles as the zero-context row (in-batch row 0) for k/v.
    fill_bias<<<3072, 256, 0, stream>>>(qb, bq + (size_t)l * 192, 192);
    fill_bias<<<3072, 256, 0, stream>>>(kb, bk + (size_t)l * 192, 192);
    fill_bias<<<3072, 256, 0, stream>>>(vb, bv + (size_t)l * 192, 192);
    gemm_qkv<0><<<dim3(32, 8), 256, 0, stream>>>(zbuf, WqkvT + (size_t)(l * 3 + 0) * WQKV, qb);
    gemm_qkv<1><<<dim3(32, 8), 256, 0, stream>>>(zbuf, WqkvT + (size_t)(l * 3 + 1) * WQKV, kb);
    gemm_qkv<1><<<dim3(32, 8), 256, 0, stream>>>(zbuf, WqkvT + (size_t)(l * 3 + 2) * WQKV, vb);
    // Attention (z_in in zbuf is dead now; attnP scratch aliases it)
    attn_pass1<<<2304, 256, 0, stream>>>(qb, kb, vb, attnP);
    attn_merge<<<4096, 192, 0, stream>>>(attnP, ob);
    // z_pred_ = relu(o @ Wo + bo) -> zpred_ (aliases zbuf; attnP dead)
    gemm_bt2<unsigned short, true, 0, true, false><<<dim3(32, 96), 256, 0, stream>>>(
        ob, WoT + (size_t)l * 12288 * 192, zpred_, bo + (size_t)l * 12288, 192, 12288, 1.0f);
    // Dz = z_pred_ @ D  (split-K=2, atomic into zero-prefilled f32)
    fill_bias<<<12288, 256, 0, stream>>>(Dz, nullptr, 768);
    gemm_bt2<float, false, 0, false, true><<<dim3(32, 6, 2), 256, 0, stream>>>(
        zpred_, Dt, Dz, nullptr, 12288, 768, 1.0f);
    proj_update<<<4096, 256, 0, stream>>>(Dz, x, xb);
  }
  // z_novel = relu(LAM * x @ D^T) -> zbuf shifted rows
  gemm_bt2<unsigned short, true, 1, false, false><<<dim3(32, 96), 256, 0, stream>>>(
      xb, Dbt, zbuf, nullptr, 768, 12288, LAM);
  topk_rows<<<4096, 256, 0, stream>>>(zbuf, idxo, valo);
  sparse_recons<<<4096, 256, 0, stream>>>(idxo, valo, x, xin, D, (float*)d_out);
}